// Round 8
// baseline (448.843 us; speedup 1.0000x reference)
//
#include <hip/hip_runtime.h>

#define HH 256
#define KK 8

typedef __attribute__((ext_vector_type(8))) short s16x8;
typedef __attribute__((ext_vector_type(4))) float f32x4;
typedef __attribute__((address_space(3))) unsigned int lds_u32;
typedef const __attribute__((address_space(1))) unsigned int glb_u32;

__device__ __forceinline__ float bf2f(unsigned short u){ unsigned x=((unsigned)u)<<16; return __builtin_bit_cast(float,x); }
__device__ __forceinline__ unsigned short f2bf(float f){ unsigned x=__builtin_bit_cast(unsigned,f); return (unsigned short)((x+0x7fffu+((x>>16)&1u))>>16); }
__device__ __forceinline__ float sigmoidf(float x){ return __builtin_amdgcn_rcpf(1.0f + __expf(-x)); }

// ---- K1: all 4 weights f32 -> bf16 in one launch.  grid (32,4) x 256thr ----
__global__ void cvt_w(const float* __restrict__ wa, const float* __restrict__ wu,
                      const float* __restrict__ wv, const float* __restrict__ wbm,
                      unsigned short* __restrict__ dst){
  const int w = blockIdx.y;
  const float* src = (w==0)? wa : (w==1)? wu : (w==2)? wv : wbm;
  const int i = blockIdx.x*256 + threadIdx.x;
  const float4* s = reinterpret_cast<const float4*>(src);
  float4 a = s[i*2], b = s[i*2+1];
  uint4 o;
  o.x = (unsigned)f2bf(a.x) | ((unsigned)f2bf(a.y)<<16);
  o.y = (unsigned)f2bf(a.z) | ((unsigned)f2bf(a.w)<<16);
  o.z = (unsigned)f2bf(b.x) | ((unsigned)f2bf(b.y)<<16);
  o.w = (unsigned)f2bf(b.z) | ((unsigned)f2bf(b.w)<<16);
  reinterpret_cast<uint4*>(dst + (size_t)w*65536)[i] = o;
}

// ---- K2: px[m][1024] = prev[m,:] @ [W_A|W_U|W_V|W_B]^T ----
// 512 thr / 8 waves; block = 128 rows x 1024 cols. A-frags in regs.
// B: 32 panels (64 cols x 128 k = 16KB), 4 LDS buffers, global_load_lds,
// counted vmcnt (T4) + single raw barrier per panel + setprio (T5).
__global__ __launch_bounds__(512, 4)
void gemm_all(const float* __restrict__ prev,
              const unsigned short* __restrict__ wb,   // [1024][256] bf16 rows = out-cols
              unsigned short* __restrict__ px,         // [N][1024] bf16
              int n)
{
  __shared__ char smem[65536];          // A-stage (64KB), then 4 x 16KB B buffers
  const int tid = threadIdx.x;
  const int m0  = blockIdx.x * 128;
  const int lane = tid & 63, wid = tid >> 6;
  const int wr = wid >> 1, wc = wid & 1;     // 4 row-groups(32) x 2 col-halves(32 of 64)
  const int lm = lane & 15, kc = lane >> 4;

  // ---- stage A-tile: 128 rows x 256k, f32->bf16, swizzled ----
  #pragma unroll
  for (int it=0; it<8; ++it){
    const int c = it*512 + tid;
    const int row = c>>5, kch = c&31;
    const int gm = m0 + row;
    uint4 o = {0u,0u,0u,0u};
    if (gm < n){
      const float4* sp = reinterpret_cast<const float4*>(prev + (size_t)gm*HH + kch*8);
      float4 f0 = sp[0], f1 = sp[1];
      o.x=(unsigned)f2bf(f0.x)|((unsigned)f2bf(f0.y)<<16);
      o.y=(unsigned)f2bf(f0.z)|((unsigned)f2bf(f0.w)<<16);
      o.z=(unsigned)f2bf(f1.x)|((unsigned)f2bf(f1.y)<<16);
      o.w=(unsigned)f2bf(f1.z)|((unsigned)f2bf(f1.w)<<16);
    }
    *reinterpret_cast<uint4*>(smem + row*512 + ((kch*16) ^ ((row&7)<<4))) = o;
  }
  __syncthreads();

  // ---- A fragments -> registers ----
  s16x8 af[2][8];
  #pragma unroll
  for (int i=0;i<2;++i){
    const int row = wr*32 + i*16 + lm;
    #pragma unroll
    for (int k8=0;k8<8;++k8)
      af[i][k8] = *reinterpret_cast<const s16x8*>(smem + row*512 + ((k8*64 + kc*16) ^ ((row&7)<<4)));
  }
  __syncthreads();        // all af reads done; smem becomes B buffers

  // per-lane pre-swizzled DMA source (linear LDS dest; swizzle on source+read)
  const int rr = lane>>4, ks16 = (lane&15)*16;
  const int off_e = rr*512 + (ks16 ^ (rr<<4));     // even chunks; odd chunks: ^64
  const char* wbc = reinterpret_cast<const char*>(wb);

  // panel P: cols [(P>>1)*64, +64), k-half (P&1). 16KB = 16 chunks of 1024B (4 rows).
  #define ISSUE_PANEL(Wp, lb)                                                      \
    { _Pragma("unroll")                                                            \
      for (int c_=0;c_<2;++c_){                                                    \
        const int chunk_ = wid*2 + c_;                                             \
        const char* ga_ = (Wp) + chunk_*2048 + ((chunk_&1)? (off_e^64) : off_e);   \
        __builtin_amdgcn_global_load_lds((glb_u32*)ga_,                            \
            (lds_u32*)((lb) + chunk_*1024), 16, 0, 0);                             \
      } }

  ISSUE_PANEL(wbc,         smem)            // P0 -> buf0
  ISSUE_PANEL(wbc + 256,   smem + 16384)    // P1 -> buf1
  ISSUE_PANEL(wbc + 32768, smem + 32768)    // P2 -> buf2

  f32x4 acc[2][2];
  for (int q=0; q<32; ++q){
    // counted wait: panel q resident; panels q+1,q+2 (2 instr each) stay in flight
    if (q < 30)       asm volatile("s_waitcnt vmcnt(4)" ::: "memory");
    else if (q == 30) asm volatile("s_waitcnt vmcnt(2)" ::: "memory");
    else              asm volatile("s_waitcnt vmcnt(0)" ::: "memory");
    __builtin_amdgcn_s_barrier();            // all waves: panel q resident, buf[(q+3)&3] free
    __builtin_amdgcn_sched_barrier(0);
    if (q < 29){
      const int p3 = q + 3;
      ISSUE_PANEL(wbc + (p3>>1)*32768 + (p3&1)*256, smem + (p3&3)*16384)
    }
    const int g = q>>1, kh = q&1;
    const char* rb = smem + (q&3)*16384;
    if (kh==0){
      acc[0][0]=(f32x4){0.f,0.f,0.f,0.f}; acc[0][1]=(f32x4){0.f,0.f,0.f,0.f};
      acc[1][0]=(f32x4){0.f,0.f,0.f,0.f}; acc[1][1]=(f32x4){0.f,0.f,0.f,0.f};
    }
    __builtin_amdgcn_s_setprio(1);
    #pragma unroll
    for (int kk=0; kk<4; ++kk){
      #pragma unroll
      for (int j=0;j<2;++j){
        const int brow = wc*32 + j*16 + lm;
        s16x8 bf = *reinterpret_cast<const s16x8*>(rb + brow*256 + ((kk*64 + kc*16) ^ ((brow&7)<<4)));
        acc[0][j] = __builtin_amdgcn_mfma_f32_16x16x32_bf16(af[0][kh*4+kk], bf, acc[0][j], 0, 0, 0);
        acc[1][j] = __builtin_amdgcn_mfma_f32_16x16x32_bf16(af[1][kh*4+kk], bf, acc[1][j], 0, 0, 0);
      }
    }
    __builtin_amdgcn_s_setprio(0);
    if (kh==1){                              // flush this 64-col group
      #pragma unroll
      for (int i=0;i<2;++i){
        #pragma unroll
        for (int r=0;r<4;++r){
          const int gm = m0 + wr*32 + i*16 + kc*4 + r;   // D: row=(lane>>4)*4+reg
          if (gm < n){
            unsigned short* dp = px + (size_t)gm*1024 + g*64 + wc*32 + lm;
            dp[0]  = f2bf(acc[i][0][r]);
            dp[16] = f2bf(acc[i][1][r]);
          }
        }
      }
    }
  }
  #undef ISSUE_PANEL
}

// ---- K3: gather epilogue. 32 lanes per node-row, 8 cols/lane. ----
__global__ __launch_bounds__(256)
void epilogue(const unsigned short* __restrict__ px,   // [N][4][256]: A,U,V,B
              const int* __restrict__ parent,
              const int* __restrict__ child,
              const int* __restrict__ mask,
              float* __restrict__ out,
              int n)
{
  const int e = blockIdx.x*8 + (threadIdx.x>>5);
  if (e >= n) return;
  const int c8 = (threadIdx.x & 31) * 8;
  const int p  = parent[e];

  const unsigned short* rp = px + (size_t)p*1024 + c8;
  uint4 av = *reinterpret_cast<const uint4*>(rp);         // PA
  uint4 uv = *reinterpret_cast<const uint4*>(rp + 256);   // PU
  const unsigned short* ap = reinterpret_cast<const unsigned short*>(&av);
  const unsigned short* up = reinterpret_cast<const unsigned short*>(&uv);

  float A[8], o[8], eta[8];
  #pragma unroll
  for (int j=0;j<8;++j){ A[j]=bf2f(ap[j]); o[j]=bf2f(up[j]); eta[j]=0.f; }

  int nm = 0;
  #pragma unroll
  for (int k=0;k<KK;++k){
    if (mask[(size_t)e*KK + k]){
      const unsigned short* rc = px + (size_t)child[(size_t)e*KK + k]*1024 + c8;
      uint4 pv = *reinterpret_cast<const uint4*>(rc + 512);   // PV
      uint4 pb = *reinterpret_cast<const uint4*>(rc + 768);   // PB
      const unsigned short* vp = reinterpret_cast<const unsigned short*>(&pv);
      const unsigned short* bp = reinterpret_cast<const unsigned short*>(&pb);
      #pragma unroll
      for (int j=0;j<8;++j){
        o[j]   += bf2f(vp[j]);
        eta[j] += sigmoidf(A[j] + bf2f(bp[j]));
      }
    } else ++nm;
  }

  const float fnm = (float)nm;
  #pragma unroll
  for (int j=0;j<8;++j){
    float s = o[j] + eta[j] + fnm * sigmoidf(A[j]);
    out[(size_t)p*HH + c8 + j] = s > 0.f ? s : 0.f;
  }
}

extern "C" void kernel_launch(void* const* d_in, const int* in_sizes, int n_in,
                              void* d_out, int out_size, void* d_ws, size_t ws_size,
                              hipStream_t stream)
{
  const float* prev = (const float*)d_in[0];
  const float* W_U  = (const float*)d_in[1];
  const float* W_V  = (const float*)d_in[2];
  const float* W_A  = (const float*)d_in[3];
  const float* W_B  = (const float*)d_in[4];
  const int* parent = (const int*)d_in[5];
  const int* child  = (const int*)d_in[6];
  const int* mask   = (const int*)d_in[7];
  float* out = (float*)d_out;

  const int n_nodes = in_sizes[5];

  unsigned short* wb = (unsigned short*)d_ws;      // [1024][256] bf16 (A,U,V,B rows)
  unsigned short* px = wb + 4*65536;               // [N][1024] bf16

  dim3 gc(32, 4);
  cvt_w<<<gc, 256, 0, stream>>>(W_A, W_U, W_V, W_B, wb);

  gemm_all<<<(n_nodes + 127)/128, 512, 0, stream>>>(prev, wb, px, n_nodes);

  epilogue<<<(n_nodes + 7)/8, 256, 0, stream>>>(px, parent, child, mask, out, n_nodes);
}

// Round 9
// 365.484 us; speedup vs baseline: 1.2281x; 1.2281x over previous
//
#include <hip/hip_runtime.h>

#define HH 256
#define KK 8

typedef __attribute__((ext_vector_type(8))) short s16x8;
typedef __attribute__((ext_vector_type(4))) float f32x4;

__device__ __forceinline__ float bf2f(unsigned short u){ unsigned x=((unsigned)u)<<16; return __builtin_bit_cast(float,x); }
__device__ __forceinline__ unsigned short f2bf(float f){ unsigned x=__builtin_bit_cast(unsigned,f); return (unsigned short)((x+0x7fffu+((x>>16)&1u))>>16); }
__device__ __forceinline__ float sigmoidf(float x){ return __builtin_amdgcn_rcpf(1.0f + __expf(-x)); }

// ---- K1: all 4 weights f32 -> bf16 in one launch.  grid (32,4) x 256thr ----
__global__ void cvt_w(const float* __restrict__ wa, const float* __restrict__ wu,
                      const float* __restrict__ wv, const float* __restrict__ wbm,
                      unsigned short* __restrict__ dst){
  const int w = blockIdx.y;
  const float* src = (w==0)? wa : (w==1)? wu : (w==2)? wv : wbm;
  const int i = blockIdx.x*256 + threadIdx.x;
  const float4* s = reinterpret_cast<const float4*>(src);
  float4 a = s[i*2], b = s[i*2+1];
  uint4 o;
  o.x = (unsigned)f2bf(a.x) | ((unsigned)f2bf(a.y)<<16);
  o.y = (unsigned)f2bf(a.z) | ((unsigned)f2bf(a.w)<<16);
  o.z = (unsigned)f2bf(b.x) | ((unsigned)f2bf(b.y)<<16);
  o.w = (unsigned)f2bf(b.z) | ((unsigned)f2bf(b.w)<<16);
  reinterpret_cast<uint4*>(dst + (size_t)w*65536)[i] = o;
}

// ---- K2: px[m][1024] = prev[m,:] @ [W_A|W_U|W_V|W_B]^T ----
// Barrier-free, LDS-free. 256 thr / 4 waves; wave owns 32 rows, streams all
// 1024 out-cols in 16-col groups with B-fragments loaded global->VGPR
// (weights are 512KB, L2-hot). A-fragments held in regs for the whole kernel.
__global__ __launch_bounds__(256, 4)
void gemm_reg(const float* __restrict__ prev,
              const unsigned short* __restrict__ wb,   // [1024][256] bf16 rows = out-cols
              unsigned short* __restrict__ px,         // [N][1024] bf16
              int n)
{
  const int tid  = threadIdx.x;
  const int lane = tid & 63, wid = tid >> 6;
  const int r0   = blockIdx.x * 128 + wid * 32;   // this wave's 32 rows
  const int lm   = lane & 15, kc = lane >> 4;

  // ---- A fragments: af[i][kk] for rows r0+i*16+lm, k-slice kk (f32 -> bf16) ----
  s16x8 af[2][8];
  #pragma unroll
  for (int i=0;i<2;++i){
    const int row = r0 + i*16 + lm;
    if (row < n){
      const char* rp = reinterpret_cast<const char*>(prev + (size_t)row * HH);
      #pragma unroll
      for (int kk=0;kk<8;++kk){
        float4 f0 = *reinterpret_cast<const float4*>(rp + kk*128 + kc*32);
        float4 f1 = *reinterpret_cast<const float4*>(rp + kk*128 + kc*32 + 16);
        s16x8 a;
        a[0]=(short)f2bf(f0.x); a[1]=(short)f2bf(f0.y);
        a[2]=(short)f2bf(f0.z); a[3]=(short)f2bf(f0.w);
        a[4]=(short)f2bf(f1.x); a[5]=(short)f2bf(f1.y);
        a[6]=(short)f2bf(f1.z); a[7]=(short)f2bf(f1.w);
        af[i][kk] = a;
      }
    } else {
      #pragma unroll
      for (int kk=0;kk<8;++kk) af[i][kk] = (s16x8){0,0,0,0,0,0,0,0};
    }
  }

  // ---- stream 64 groups of 16 out-cols; no sync anywhere ----
  const char* wbc = reinterpret_cast<const char*>(wb);
  for (int cg=0; cg<64; ++cg){
    const char* bp = wbc + (size_t)(cg*16 + lm)*512 + kc*16;
    f32x4 acc0 = {0.f,0.f,0.f,0.f}, acc1 = {0.f,0.f,0.f,0.f};
    s16x8 b[8];
    #pragma unroll
    for (int kk=0;kk<8;++kk) b[kk] = *reinterpret_cast<const s16x8*>(bp + kk*64);
    #pragma unroll
    for (int kk=0;kk<8;++kk){
      acc0 = __builtin_amdgcn_mfma_f32_16x16x32_bf16(af[0][kk], b[kk], acc0, 0, 0, 0);
      acc1 = __builtin_amdgcn_mfma_f32_16x16x32_bf16(af[1][kk], b[kk], acc1, 0, 0, 0);
    }
    // D: col=lane&15, row=(lane>>4)*4+reg
    #pragma unroll
    for (int r=0;r<4;++r){
      const int row0 = r0 + kc*4 + r;
      if (row0 < n)      px[(size_t)row0*1024 + cg*16 + lm]      = f2bf(acc0[r]);
      const int row1 = row0 + 16;
      if (row1 < n)      px[(size_t)row1*1024 + cg*16 + lm]      = f2bf(acc1[r]);
    }
  }
}

// ---- K3: gather epilogue. 32 lanes per node-row, 8 cols/lane. ----
__global__ __launch_bounds__(256)
void epilogue(const unsigned short* __restrict__ px,   // [N][4][256]: A,U,V,B
              const int* __restrict__ parent,
              const int* __restrict__ child,
              const int* __restrict__ mask,
              float* __restrict__ out,
              int n)
{
  const int e = blockIdx.x*8 + (threadIdx.x>>5);
  if (e >= n) return;
  const int c8 = (threadIdx.x & 31) * 8;
  const int p  = parent[e];

  const unsigned short* rp = px + (size_t)p*1024 + c8;
  uint4 av = *reinterpret_cast<const uint4*>(rp);         // PA
  uint4 uv = *reinterpret_cast<const uint4*>(rp + 256);   // PU
  const unsigned short* ap = reinterpret_cast<const unsigned short*>(&av);
  const unsigned short* up = reinterpret_cast<const unsigned short*>(&uv);

  float A[8], o[8], eta[8];
  #pragma unroll
  for (int j=0;j<8;++j){ A[j]=bf2f(ap[j]); o[j]=bf2f(up[j]); eta[j]=0.f; }

  int nm = 0;
  #pragma unroll
  for (int k=0;k<KK;++k){
    if (mask[(size_t)e*KK + k]){
      const unsigned short* rc = px + (size_t)child[(size_t)e*KK + k]*1024 + c8;
      uint4 pv = *reinterpret_cast<const uint4*>(rc + 512);   // PV
      uint4 pb = *reinterpret_cast<const uint4*>(rc + 768);   // PB
      const unsigned short* vp = reinterpret_cast<const unsigned short*>(&pv);
      const unsigned short* bp = reinterpret_cast<const unsigned short*>(&pb);
      #pragma unroll
      for (int j=0;j<8;++j){
        o[j]   += bf2f(vp[j]);
        eta[j] += sigmoidf(A[j] + bf2f(bp[j]));
      }
    } else ++nm;
  }

  const float fnm = (float)nm;
  #pragma unroll
  for (int j=0;j<8;++j){
    float s = o[j] + eta[j] + fnm * sigmoidf(A[j]);
    out[(size_t)p*HH + c8 + j] = s > 0.f ? s : 0.f;
  }
}

extern "C" void kernel_launch(void* const* d_in, const int* in_sizes, int n_in,
                              void* d_out, int out_size, void* d_ws, size_t ws_size,
                              hipStream_t stream)
{
  const float* prev = (const float*)d_in[0];
  const float* W_U  = (const float*)d_in[1];
  const float* W_V  = (const float*)d_in[2];
  const float* W_A  = (const float*)d_in[3];
  const float* W_B  = (const float*)d_in[4];
  const int* parent = (const int*)d_in[5];
  const int* child  = (const int*)d_in[6];
  const int* mask   = (const int*)d_in[7];
  float* out = (float*)d_out;

  const int n_nodes = in_sizes[5];

  unsigned short* wb = (unsigned short*)d_ws;      // [1024][256] bf16 (A,U,V,B rows)
  unsigned short* px = wb + 4*65536;               // [N][1024] bf16

  dim3 gc(32, 4);
  cvt_w<<<gc, 256, 0, stream>>>(W_A, W_U, W_V, W_B, wb);

  gemm_reg<<<(n_nodes + 127)/128, 256, 0, stream>>>(prev, wb, px, n_nodes);

  epilogue<<<(n_nodes + 7)/8, 256, 0, stream>>>(px, parent, child, mask, out, n_nodes);
}

// Round 10
// 244.768 us; speedup vs baseline: 1.8337x; 1.4932x over previous
//
#include <hip/hip_runtime.h>

#define HH 256
#define KK 8

typedef __attribute__((ext_vector_type(8))) short s16x8;
typedef __attribute__((ext_vector_type(4))) float f32x4;
typedef __attribute__((address_space(3))) unsigned int lds_u32;
typedef const __attribute__((address_space(1))) unsigned int glb_u32;

__device__ __forceinline__ float bf2f(unsigned short u){ unsigned x=((unsigned)u)<<16; return __builtin_bit_cast(float,x); }
__device__ __forceinline__ unsigned short f2bf(float f){ unsigned x=__builtin_bit_cast(unsigned,f); return (unsigned short)((x+0x7fffu+((x>>16)&1u))>>16); }
__device__ __forceinline__ float sigmoidf(float x){ return __builtin_amdgcn_rcpf(1.0f + __expf(-x)); }

// ---- K1: all 4 weights f32 -> bf16.  grid (32,4) x 256thr ----
__global__ void cvt_w(const float* __restrict__ wa, const float* __restrict__ wu,
                      const float* __restrict__ wv, const float* __restrict__ wbm,
                      unsigned short* __restrict__ dst){
  const int w = blockIdx.y;
  const float* src = (w==0)? wa : (w==1)? wu : (w==2)? wv : wbm;
  const int i = blockIdx.x*256 + threadIdx.x;
  const float4* s = reinterpret_cast<const float4*>(src);
  float4 a = s[i*2], b = s[i*2+1];
  uint4 o;
  o.x = (unsigned)f2bf(a.x) | ((unsigned)f2bf(a.y)<<16);
  o.y = (unsigned)f2bf(a.z) | ((unsigned)f2bf(a.w)<<16);
  o.z = (unsigned)f2bf(b.x) | ((unsigned)f2bf(b.y)<<16);
  o.w = (unsigned)f2bf(b.z) | ((unsigned)f2bf(b.w)<<16);
  reinterpret_cast<uint4*>(dst + (size_t)w*65536)[i] = o;
}

// ---- K2: px[m][1024] = prev[m,:] @ [W_A|W_U|W_V|W_B]^T ----
// 512 thr / 8 waves; block = 128 rows x 1024 cols. A-frags in regs.
// 32 panels (64 cols x 128 k = 16KB) x 2 LDS buffers via global_load_lds.
// px written through a swizzled LDS bounce -> dwordx4 contiguous stores.
__global__ __launch_bounds__(512, 4)
void gemm_all(const float* __restrict__ prev,
              const unsigned short* __restrict__ wb,   // [1024][256] bf16 rows = out-cols
              unsigned short* __restrict__ px,         // [N][1024] bf16
              int n)
{
  __shared__ char smem[65536];   // A-stage 64KB; then B dbuf 2x16KB + bounce 2x16KB
  const int tid = threadIdx.x;
  const int m0  = blockIdx.x * 128;
  const int lane = tid & 63, wid = tid >> 6;
  const int wr = wid >> 1, wc = wid & 1;   // 4 row-groups(32) x 2 col-halves(32)
  const int lm = lane & 15, kc = lane >> 4;

  // ---- stage A-tile: 128 rows x 256k, f32->bf16, swizzled ----
  #pragma unroll
  for (int it=0; it<8; ++it){
    const int c = it*512 + tid;
    const int row = c>>5, kch = c&31;
    const int gm = m0 + row;
    uint4 o = {0u,0u,0u,0u};
    if (gm < n){
      const float4* sp = reinterpret_cast<const float4*>(prev + (size_t)gm*HH + kch*8);
      float4 f0 = sp[0], f1 = sp[1];
      o.x=(unsigned)f2bf(f0.x)|((unsigned)f2bf(f0.y)<<16);
      o.y=(unsigned)f2bf(f0.z)|((unsigned)f2bf(f0.w)<<16);
      o.z=(unsigned)f2bf(f1.x)|((unsigned)f2bf(f1.y)<<16);
      o.w=(unsigned)f2bf(f1.z)|((unsigned)f2bf(f1.w)<<16);
    }
    *reinterpret_cast<uint4*>(smem + row*512 + ((kch*16) ^ ((row&7)<<4))) = o;
  }
  __syncthreads();

  // ---- A fragments -> registers ----
  s16x8 af[2][8];
  #pragma unroll
  for (int i=0;i<2;++i){
    const int row = wr*32 + i*16 + lm;
    #pragma unroll
    for (int k8=0;k8<8;++k8)
      af[i][k8] = *reinterpret_cast<const s16x8*>(smem + row*512 + ((k8*64 + kc*16) ^ ((row&7)<<4)));
  }
  __syncthreads();        // A-stage region free -> B dbuf [0,32K) + bounce [32K,64K)

  // DMA source pre-swizzle (linear LDS dest = base + lane*16):
  // chunk k_: rows g*64 + k_*4 + (lane>>4); byte (lane&15)*16 ^ ((k_&1)*4+(lane>>4))<<4
  const int rr4  = lane >> 4;
  const int inner = (lane & 15) * 16;
  const char* wbc = reinterpret_cast<const char*>(wb);

  #define ISSUE_PANEL(Wp, lb)                                                       \
    { _Pragma("unroll")                                                             \
      for (int c_=0;c_<2;++c_){                                                     \
        const int k_ = wid*2 + c_;                                                  \
        const int s_ = ((c_&1)*4 + rr4) << 4;                                       \
        const char* ga_ = (Wp) + k_*2048 + rr4*512 + (inner ^ s_);                  \
        __builtin_amdgcn_global_load_lds((glb_u32*)ga_,                             \
            (lds_u32*)((lb) + k_*1024), 16, 0, 0);                                  \
      } }

  #define WRITE_BOUNCE(g_)                                                          \
    { char* bb = smem + 32768 + ((g_)&1)*16384;                                     \
      _Pragma("unroll")                                                             \
      for (int i=0;i<2;++i){                                                        \
        _Pragma("unroll")                                                           \
        for (int j=0;j<2;++j){                                                      \
          _Pragma("unroll")                                                         \
          for (int r=0;r<4;++r){                                                    \
            const int row = wr*32 + i*16 + kc*4 + r;                                \
            const int col = wc*32 + j*16 + lm;                                      \
            *reinterpret_cast<unsigned short*>(bb + row*128 + ((col*2) ^ ((row&7)<<4))) \
                = f2bf(acc[i][j][r]);                                               \
          } } } }

  #define READBACK(gp)                                                              \
    { const char* bb = smem + 32768 + ((gp)&1)*16384;                               \
      _Pragma("unroll")                                                             \
      for (int pass=0; pass<2; ++pass){                                             \
        const int c2 = pass*512 + tid;                                              \
        const int row = c2>>3, ch = c2&7;                                           \
        const int gm = m0 + row;                                                    \
        if (gm < n){                                                                \
          uint4 v = *reinterpret_cast<const uint4*>(bb + row*128 + ((ch*16) ^ ((row&7)<<4))); \
          *reinterpret_cast<uint4*>(px + (size_t)gm*1024 + (gp)*64 + ch*8) = v;     \
        } } }

  ISSUE_PANEL(wbc, smem)          // P0 -> buf0

  f32x4 acc[2][2];
  for (int q=0; q<32; ++q){
    const int g = q>>1, kh = q&1;
    __syncthreads();               // panel q resident; buf[(q+1)&1] free; bounce[(g-1)&1] written
    if (q < 31){
      const int p1 = q + 1;
      ISSUE_PANEL(wbc + (p1>>1)*32768 + (p1&1)*256, smem + (p1&1)*16384)
    }
    if (kh==0){
      if (g > 0) READBACK(g-1)     // overlaps this step's MFMA phase
      acc[0][0]=(f32x4){0.f,0.f,0.f,0.f}; acc[0][1]=(f32x4){0.f,0.f,0.f,0.f};
      acc[1][0]=(f32x4){0.f,0.f,0.f,0.f}; acc[1][1]=(f32x4){0.f,0.f,0.f,0.f};
    }
    const char* rb = smem + (q&1)*16384;
    #pragma unroll
    for (int kk=0; kk<4; ++kk){
      #pragma unroll
      for (int j=0;j<2;++j){
        const int brow = wc*32 + j*16 + lm;
        s16x8 bf = *reinterpret_cast<const s16x8*>(rb + brow*256 + ((kk*64 + kc*16) ^ ((brow&7)<<4)));
        acc[0][j] = __builtin_amdgcn_mfma_f32_16x16x32_bf16(af[0][kh*4+kk], bf, acc[0][j], 0, 0, 0);
        acc[1][j] = __builtin_amdgcn_mfma_f32_16x16x32_bf16(af[1][kh*4+kk], bf, acc[1][j], 0, 0, 0);
      }
    }
    if (kh==1) WRITE_BOUNCE(g)
  }
  __syncthreads();
  READBACK(15)
  #undef ISSUE_PANEL
  #undef WRITE_BOUNCE
  #undef READBACK
}

// ---- K3: gather epilogue. 64 lanes per node, 4 cols/lane; fat loads/stores. ----
__global__ __launch_bounds__(256)
void epilogue(const unsigned short* __restrict__ px,   // [N][4][256]: A,U,V,B
              const int* __restrict__ parent,
              const int* __restrict__ child,
              const int* __restrict__ mask,
              float* __restrict__ out,
              int n)
{
  const int e = blockIdx.x*4 + (threadIdx.x>>6);   // wave-uniform node
  if (e >= n) return;
  const int c4 = (threadIdx.x & 63) * 4;
  const int p  = parent[e];

  const unsigned short* rp = px + (size_t)p*1024 + c4;
  uint2 av = *reinterpret_cast<const uint2*>(rp);         // PA (4 bf16)
  uint2 uv = *reinterpret_cast<const uint2*>(rp + 256);   // PU
  const unsigned short* ap = reinterpret_cast<const unsigned short*>(&av);
  const unsigned short* up = reinterpret_cast<const unsigned short*>(&uv);

  float A[4], o[4], eta[4];
  #pragma unroll
  for (int j=0;j<4;++j){ A[j]=bf2f(ap[j]); o[j]=bf2f(up[j]); eta[j]=0.f; }

  int nm = 0;
  #pragma unroll
  for (int k=0;k<KK;++k){
    if (mask[(size_t)e*KK + k]){
      const unsigned short* rc = px + (size_t)child[(size_t)e*KK + k]*1024 + c4;
      uint2 pv = *reinterpret_cast<const uint2*>(rc + 512);   // PV
      uint2 pb = *reinterpret_cast<const uint2*>(rc + 768);   // PB
      const unsigned short* vp = reinterpret_cast<const unsigned short*>(&pv);
      const unsigned short* bp = reinterpret_cast<const unsigned short*>(&pb);
      #pragma unroll
      for (int j=0;j<4;++j){
        o[j]   += bf2f(vp[j]);
        eta[j] += sigmoidf(A[j] + bf2f(bp[j]));
      }
    } else ++nm;
  }

  const float fnm = (float)nm;
  float4 r;
  {
    float v0 = o[0] + eta[0] + fnm*sigmoidf(A[0]);
    float v1 = o[1] + eta[1] + fnm*sigmoidf(A[1]);
    float v2 = o[2] + eta[2] + fnm*sigmoidf(A[2]);
    float v3 = o[3] + eta[3] + fnm*sigmoidf(A[3]);
    r.x = v0>0.f?v0:0.f; r.y = v1>0.f?v1:0.f;
    r.z = v2>0.f?v2:0.f; r.w = v3>0.f?v3:0.f;
  }
  *reinterpret_cast<float4*>(out + (size_t)p*HH + c4) = r;
}

extern "C" void kernel_launch(void* const* d_in, const int* in_sizes, int n_in,
                              void* d_out, int out_size, void* d_ws, size_t ws_size,
                              hipStream_t stream)
{
  const float* prev = (const float*)d_in[0];
  const float* W_U  = (const float*)d_in[1];
  const float* W_V  = (const float*)d_in[2];
  const float* W_A  = (const float*)d_in[3];
  const float* W_B  = (const float*)d_in[4];
  const int* parent = (const int*)d_in[5];
  const int* child  = (const int*)d_in[6];
  const int* mask   = (const int*)d_in[7];
  float* out = (float*)d_out;

  const int n_nodes = in_sizes[5];

  unsigned short* wb = (unsigned short*)d_ws;      // [1024][256] bf16 (A,U,V,B rows)
  unsigned short* px = wb + 4*65536;               // [N][1024] bf16

  dim3 gc(32, 4);
  cvt_w<<<gc, 256, 0, stream>>>(W_A, W_U, W_V, W_B, wb);

  gemm_all<<<(n_nodes + 127)/128, 512, 0, stream>>>(prev, wb, px, n_nodes);

  epilogue<<<(n_nodes + 3)/4, 256, 0, stream>>>(px, parent, child, mask, out, n_nodes);
}